// Round 9
// baseline (195.905 us; speedup 1.0000x reference)
//
#include <hip/hip_runtime.h>
#include <hip/hip_bf16.h>

#define NN 50000
#define NE 600000
#define DD 128
#define CAP 48               // max degree slots; P(Poisson(12) >= 48) ~ 3e-15

typedef __attribute__((ext_vector_type(8))) short short8_t;
typedef __attribute__((ext_vector_type(4))) short short4_t;
typedef __attribute__((ext_vector_type(4))) float f32x4;

__device__ __forceinline__ short f2bf(float f) {
    union { float f; unsigned u; } v; v.f = f;
    unsigned r = (v.u + 0x7FFFu + ((v.u >> 16) & 1u)) >> 16;
    return (short)r;
}
__device__ __forceinline__ float bflo(unsigned x) { return __uint_as_float(x << 16); }
__device__ __forceinline__ float bfhi(unsigned x) { return __uint_as_float(x & 0xffff0000u); }

// ---- K0: prep — zero counts; build linear bf16 copies of pool_w and lin_w ----
__global__ __launch_bounds__(256) void prep(const float* __restrict__ pw,
        const float* __restrict__ lw, unsigned short* __restrict__ w1,
        unsigned short* __restrict__ w2, int* __restrict__ counts)
{
    const int b = blockIdx.x, t = threadIdx.x;
    if (b < 196) {                       // 196*256 = 50176 >= 50000
        int i = b * 256 + t;
        if (i < NN) counts[i] = 0;
    } else if (b < 212) {                // pool_w: 16384 f32 / 16 blocks
        int base = (b - 196) * 1024 + t * 4;
        float4 v = *(const float4*)(pw + base);
        short4_t s4 = { f2bf(v.x), f2bf(v.y), f2bf(v.z), f2bf(v.w) };
        *(short4_t*)(w1 + base) = s4;
    } else {                             // lin_w
        int base = (b - 212) * 1024 + t * 4;
        float4 v = *(const float4*)(lw + base);
        short4_t s4 = { f2bf(v.x), f2bf(v.y), f2bf(v.z), f2bf(v.w) };
        *(short4_t*)(w2 + base) = s4;
    }
}

// ---- zero-LDS GEMM: out = act(A @ Wb^T + b1 [+ b2]) ----
// N=K=128: each A element feeds exactly ONE lane once -> LDS staging of A has
// zero reuse; W (32 KB bf16) is L2-resident, so b-frags load straight from
// global too. No LDS, no barrier: pure load->MFMA->store dataflow, occupancy
// capped by threads only (32 waves/CU). BM=64, 512 thr = 4 row-groups x 2
// col-halves; per wave 16 MFMA, acc = 4 x f32x4.
template<bool RELU, bool B2, bool IN_BF, bool OUT_BF>
__global__ __launch_bounds__(512) void gemmz(const void* __restrict__ Av,
        const unsigned short* __restrict__ Wb, const float* __restrict__ b1,
        const float* __restrict__ b2, void* __restrict__ outv, int M)
{
    const int tid = threadIdx.x;
    const int lane = tid & 63, wid = tid >> 6;
    const int l15 = lane & 15, lhi = lane >> 4;
    const int rg = wid & 3, cs = wid >> 2;
    const int m0 = blockIdx.x * 64 + rg * 16;
    const int ar = m0 + l15;

    // B fragments: wave's col-half cs -> W rows cs*64 .. cs*64+63
    short8_t bf[4][4];
    #pragma unroll
    for (int t = 0; t < 4; ++t) {
        const int br = cs * 64 + t * 16 + l15;
        #pragma unroll
        for (int kk = 0; kk < 4; ++kk)
            bf[t][kk] = *(const short8_t*)(Wb + br * 128 + kk * 32 + lhi * 8);
    }

    // A fragments (row ar, col chunk kk*32+lhi*8 .. +7)
    short8_t af[4];
    if (IN_BF) {
        // A lives in d_ws; rows >= M read adjacent mapped ws bytes (finite bf16
        // garbage), results unstored -> safe, no clamp needed.
        const unsigned short* A = (const unsigned short*)Av;
        #pragma unroll
        for (int kk = 0; kk < 4; ++kk)
            af[kk] = *(const short8_t*)(A + (size_t)ar * 128 + kk * 32 + lhi * 8);
    } else {
        // A is a harness input buffer: clamp row to avoid OOB fault.
        const int arc = min(ar, M - 1);
        const float* A = (const float*)Av;
        #pragma unroll
        for (int kk = 0; kk < 4; ++kk) {
            float4 u = *(const float4*)(A + (size_t)arc * 128 + kk * 32 + lhi * 8);
            float4 v = *(const float4*)(A + (size_t)arc * 128 + kk * 32 + lhi * 8 + 4);
            af[kk] = short8_t{ f2bf(u.x), f2bf(u.y), f2bf(u.z), f2bf(u.w),
                               f2bf(v.x), f2bf(v.y), f2bf(v.z), f2bf(v.w) };
        }
    }

    f32x4 acc[4];
    #pragma unroll
    for (int t = 0; t < 4; ++t) acc[t] = f32x4{0.f, 0.f, 0.f, 0.f};

    #pragma unroll
    for (int kk = 0; kk < 4; ++kk) {
        #pragma unroll
        for (int t = 0; t < 4; ++t)
            acc[t] = __builtin_amdgcn_mfma_f32_16x16x32_bf16(af[kk], bf[t][kk],
                                                             acc[t], 0, 0, 0);
    }

    // epilogue: D col = cs*64 + t*16 + (lane&15), row = m0 + (lane>>4)*4 + i
    #pragma unroll
    for (int t = 0; t < 4; ++t) {
        const int c = cs * 64 + t * 16 + l15;
        float add = b1[c];
        if (B2) add += b2[c];
        #pragma unroll
        for (int i = 0; i < 4; ++i) {
            int r = m0 + lhi * 4 + i;
            if (r < M) {
                float v = acc[t][i] + add;
                if (RELU) v = fmaxf(v, 0.f);
                if (OUT_BF) ((unsigned short*)outv)[(size_t)r * 128 + c] = (unsigned short)f2bf(v);
                else        ((float*)outv)[(size_t)r * 128 + c] = v;
            }
        }
    }
}

// ---- bucket scatter, packed 4B records: (src << 16) | bf16_bits(w) ----
__global__ __launch_bounds__(256) void bucket(const int* __restrict__ src,
        const int* __restrict__ dst, const float* __restrict__ ew,
        int* __restrict__ counts, unsigned* __restrict__ edges)
{
    int e = blockIdx.x * 256 + threadIdx.x;
    if (e >= NE) return;
    int d = dst[e];
    int pos = atomicAdd(&counts[d], 1);
    if (pos < CAP)
        edges[(size_t)d * CAP + pos] =
            ((unsigned)src[e] << 16) | (unsigned short)f2bf(ew[e]);
}

// gather NIT*8 edges fully unrolled (2*NIT independent 16B loads in flight)
template<int NIT>
__device__ __forceinline__ void gat(const unsigned short* __restrict__ hb,
        unsigned p, int deg, int g, int l16, float* m)
{
    #pragma unroll
    for (int it = 0; it < NIT; ++it) {
        const int ia = it * 8 + g, ib = it * 8 + 4 + g;
        unsigned pa = __shfl(p, ia), pb = __shfl(p, ib);
        float wa = (ia < deg) ? __uint_as_float(pa << 16) : 0.f;
        float wb = (ib < deg) ? __uint_as_float(pb << 16) : 0.f;
        uint4 ra = *(const uint4*)(hb + (size_t)(pa >> 16) * 128 + l16 * 8);
        uint4 rb = *(const uint4*)(hb + (size_t)(pb >> 16) * 128 + l16 * 8);
        m[0] = fmaxf(m[0], bflo(ra.x) * wa); m[1] = fmaxf(m[1], bfhi(ra.x) * wa);
        m[2] = fmaxf(m[2], bflo(ra.y) * wa); m[3] = fmaxf(m[3], bfhi(ra.y) * wa);
        m[4] = fmaxf(m[4], bflo(ra.z) * wa); m[5] = fmaxf(m[5], bfhi(ra.z) * wa);
        m[6] = fmaxf(m[6], bflo(ra.w) * wa); m[7] = fmaxf(m[7], bfhi(ra.w) * wa);
        m[0] = fmaxf(m[0], bflo(rb.x) * wb); m[1] = fmaxf(m[1], bfhi(rb.x) * wb);
        m[2] = fmaxf(m[2], bflo(rb.y) * wb); m[3] = fmaxf(m[3], bfhi(rb.y) * wb);
        m[4] = fmaxf(m[4], bflo(rb.z) * wb); m[5] = fmaxf(m[5], bfhi(rb.z) * wb);
        m[6] = fmaxf(m[6], bflo(rb.w) * wb); m[7] = fmaxf(m[7], bfhi(rb.w) * wb);
    }
}

// ---- per-node gather+max. One wave/node; 4 lane-groups of 16; wave-uniform
// deg branch picks fully-unrolled path. Linear bf16 in/out.
__global__ __launch_bounds__(256) void node_max(const unsigned short* __restrict__ hb,
        const int* __restrict__ counts, const unsigned* __restrict__ edges,
        unsigned short* __restrict__ hnew)
{
    int node = blockIdx.x * 4 + (threadIdx.x >> 6);
    if (node >= NN) return;
    const int lane = threadIdx.x & 63;
    const int g = lane >> 4, l16 = lane & 15;
    const int deg = min(counts[node], CAP);
    const unsigned* ep = edges + (size_t)node * CAP;
    unsigned p = (lane < deg) ? ep[lane] : 0u;

    float m[8];
    #pragma unroll
    for (int i = 0; i < 8; ++i) m[i] = 0.f;

    if (deg <= 16)      gat<2>(hb, p, deg, g, l16, m);
    else if (deg <= 32) gat<4>(hb, p, deg, g, l16, m);
    else                gat<6>(hb, p, deg, g, l16, m);

    #pragma unroll
    for (int i = 0; i < 8; ++i) {
        m[i] = fmaxf(m[i], __shfl_xor(m[i], 16));
        m[i] = fmaxf(m[i], __shfl_xor(m[i], 32));
    }

    if (g == 0) {
        uint4 o;
        o.x = ((unsigned)(unsigned short)f2bf(m[1]) << 16) | (unsigned short)f2bf(m[0]);
        o.y = ((unsigned)(unsigned short)f2bf(m[3]) << 16) | (unsigned short)f2bf(m[2]);
        o.z = ((unsigned)(unsigned short)f2bf(m[5]) << 16) | (unsigned short)f2bf(m[4]);
        o.w = ((unsigned)(unsigned short)f2bf(m[7]) << 16) | (unsigned short)f2bf(m[6]);
        *(uint4*)(hnew + (size_t)node * 128 + l16 * 8) = o;
    }
}

extern "C" void kernel_launch(void* const* d_in, const int* in_sizes, int n_in,
                              void* d_out, int out_size, void* d_ws, size_t ws_size,
                              hipStream_t stream) {
    const float* node_feats = (const float*)d_in[0];
    const int*   src        = (const int*)d_in[1];
    const int*   dst        = (const int*)d_in[2];
    const float* ew         = (const float*)d_in[3];
    const float* pool_w     = (const float*)d_in[4];
    const float* pool_b     = (const float*)d_in[5];
    const float* lin_w      = (const float*)d_in[6];
    const float* lin_b      = (const float*)d_in[7];
    const float* bias       = (const float*)d_in[8];
    float* out = (float*)d_out;

    char* w0 = (char*)d_ws;
    unsigned short* hsrc = (unsigned short*)w0;  w0 += (size_t)NN * DD * 2;   // 12.8 MB
    unsigned short* hnew = (unsigned short*)w0;  w0 += (size_t)NN * DD * 2;   // 12.8 MB
    int* counts = (int*)w0;                      w0 += (size_t)NN * 4;        // 200 KB
    unsigned* edges = (unsigned*)w0;             w0 += (size_t)NN * CAP * 4;  // 9.6 MB
    unsigned short* w1b = (unsigned short*)w0;   w0 += (size_t)DD * DD * 2;   // 32 KB
    unsigned short* w2b = (unsigned short*)w0;   w0 += (size_t)DD * DD * 2;   // 32 KB

    prep<<<228, 256, 0, stream>>>(pool_w, lin_w, w1b, w2b, counts);

    const int gz_grid = (NN + 63) / 64;   // 782
    gemmz<true, false, false, true><<<gz_grid, 512, 0, stream>>>(node_feats,
            w1b, pool_b, nullptr, hsrc, NN);

    bucket<<<(NE + 255) / 256, 256, 0, stream>>>(src, dst, ew, counts, edges);

    node_max<<<(NN + 3) / 4, 256, 0, stream>>>(hsrc, counts, edges, hnew);

    gemmz<false, true, true, false><<<gz_grid, 512, 0, stream>>>(hnew,
            w2b, lin_b, bias, out, NN);
}

// Round 10
// 187.567 us; speedup vs baseline: 1.0445x; 1.0445x over previous
//
#include <hip/hip_runtime.h>
#include <hip/hip_bf16.h>

#define NN 50000
#define NE 600000
#define DD 128
#define CAP 48               // max degree slots; P(Poisson(12) >= 48) ~ 3e-15

typedef __attribute__((ext_vector_type(8))) short short8_t;
typedef __attribute__((ext_vector_type(4))) short short4_t;
typedef __attribute__((ext_vector_type(4))) float f32x4;

__device__ __forceinline__ short f2bf(float f) {
    union { float f; unsigned u; } v; v.f = f;
    unsigned r = (v.u + 0x7FFFu + ((v.u >> 16) & 1u)) >> 16;
    return (short)r;
}
__device__ __forceinline__ float bflo(unsigned x) { return __uint_as_float(x << 16); }
__device__ __forceinline__ float bfhi(unsigned x) { return __uint_as_float(x & 0xffff0000u); }

// async global->LDS, 16B/lane; dest wave-uniform base (HW adds lane*16)
__device__ __forceinline__ void gl16(const void* g, void* l) {
    __builtin_amdgcn_global_load_lds(
        (const __attribute__((address_space(1))) unsigned*)g,
        (__attribute__((address_space(3))) unsigned*)l, 16, 0, 0);
}

// ---- K0: prep — linear bf16 images of pool_w / lin_w (L1-resident for JIT B) ----
__global__ __launch_bounds__(256) void prep(const float* __restrict__ pw,
        const float* __restrict__ lw, unsigned short* __restrict__ w1,
        unsigned short* __restrict__ w2)
{
    const int b = blockIdx.x, t = threadIdx.x;
    const float* s = (b < 16) ? pw : lw;
    unsigned short* d = (b < 16) ? w1 : w2;
    int base = (b & 15) * 1024 + t * 4;
    float4 v = *(const float4*)(s + base);
    short4_t s4 = { f2bf(v.x), f2bf(v.y), f2bf(v.z), f2bf(v.w) };
    *(short4_t*)(d + base) = s4;
}

// ---- K1: hsrc = relu(X @ pool_w^T + pool_b), bf16 LINEAR out; zeroes counts ----
// BM=64, 512 thr (4 row-groups x 2 col-halves). A staged in 16KB LDS (coalesced
// f32 load + convert, XOR-swizzled); W read JIT per-fragment from bf16 image
// (32KB, L1-resident -> reuse without LDS). Occupancy: 16KB LDS, ~64 VGPR.
__global__ __launch_bounds__(512) void gemm1(const float* __restrict__ A,
        const unsigned short* __restrict__ Wb, const float* __restrict__ b1,
        unsigned short* __restrict__ hout, int* __restrict__ counts)
{
    __shared__ short aL[64 * 128];   // 16 KB
    const int tid = threadIdx.x;
    const int m0 = blockIdx.x * 64;

    {   // zero counts (stream-ordered before bucket)
        int gid = blockIdx.x * 512 + tid;
        if (gid < NN) counts[gid] = 0;
    }

    // stage A tile 64x128 (f32 -> bf16, swizzled, coalesced)
    #pragma unroll
    for (int i = 0; i < 4; ++i) {
        int flat = i * 2048 + tid * 4;
        int row = flat >> 7, k = flat & 127;
        int gr = m0 + row;
        float4 v = make_float4(0.f, 0.f, 0.f, 0.f);
        if (gr < NN) v = *(const float4*)(A + (size_t)gr * 128 + k);
        short4_t s4 = { f2bf(v.x), f2bf(v.y), f2bf(v.z), f2bf(v.w) };
        *(short4_t*)(aL + ((row * 128 + k) ^ ((row & 7) << 3))) = s4;
    }
    __syncthreads();

    const int lane = tid & 63, wid = tid >> 6;
    const int l15 = lane & 15, lhi = lane >> 4;
    const int rg = wid & 3, cs = wid >> 2;
    const int r0 = rg * 16;

    short8_t af[4];
    #pragma unroll
    for (int kk = 0; kk < 4; ++kk) {
        const int ar = r0 + l15;
        af[kk] = *(short8_t*)(aL + ((ar * 128 + kk * 32 + lhi * 8) ^ ((ar & 7) << 3)));
    }

    f32x4 acc[4];
    #pragma unroll
    for (int t = 0; t < 4; ++t) acc[t] = f32x4{0.f, 0.f, 0.f, 0.f};

    #pragma unroll
    for (int t = 0; t < 4; ++t) {
        const int br = cs * 64 + t * 16 + l15;
        #pragma unroll
        for (int kk = 0; kk < 4; ++kk) {
            short8_t b = *(const short8_t*)(Wb + br * 128 + kk * 32 + lhi * 8);
            acc[t] = __builtin_amdgcn_mfma_f32_16x16x32_bf16(af[kk], b, acc[t], 0, 0, 0);
        }
    }

    #pragma unroll
    for (int t = 0; t < 4; ++t) {
        const int c = cs * 64 + t * 16 + l15;
        float add = b1[c];
        #pragma unroll
        for (int i = 0; i < 4; ++i) {
            int r = m0 + r0 + lhi * 4 + i;
            if (r < NN) {
                float v = fmaxf(acc[t][i] + add, 0.f);
                hout[(size_t)r * 128 + c] = (unsigned short)f2bf(v);
            }
        }
    }
}

// ---- K2: bucket scatter, packed 4B records: (src << 16) | bf16_bits(w) ----
__global__ __launch_bounds__(256) void bucket(const int* __restrict__ src,
        const int* __restrict__ dst, const float* __restrict__ ew,
        int* __restrict__ counts, unsigned* __restrict__ edges)
{
    int e = blockIdx.x * 256 + threadIdx.x;
    if (e >= NE) return;
    int d = dst[e];
    int pos = atomicAdd(&counts[d], 1);
    if (pos < CAP)
        edges[(size_t)d * CAP + pos] =
            ((unsigned)src[e] << 16) | (unsigned short)f2bf(ew[e]);
}

// gather NIT*8 edges fully unrolled (2*NIT independent 16B loads in flight)
template<int NIT>
__device__ __forceinline__ void gat(const unsigned short* __restrict__ hb,
        unsigned p, int deg, int g, int l16, float* m)
{
    #pragma unroll
    for (int it = 0; it < NIT; ++it) {
        const int ia = it * 8 + g, ib = it * 8 + 4 + g;
        unsigned pa = __shfl(p, ia), pb = __shfl(p, ib);
        float wa = (ia < deg) ? __uint_as_float(pa << 16) : 0.f;
        float wb = (ib < deg) ? __uint_as_float(pb << 16) : 0.f;
        uint4 ra = *(const uint4*)(hb + (size_t)(pa >> 16) * 128 + l16 * 8);
        uint4 rb = *(const uint4*)(hb + (size_t)(pb >> 16) * 128 + l16 * 8);
        m[0] = fmaxf(m[0], bflo(ra.x) * wa); m[1] = fmaxf(m[1], bfhi(ra.x) * wa);
        m[2] = fmaxf(m[2], bflo(ra.y) * wa); m[3] = fmaxf(m[3], bfhi(ra.y) * wa);
        m[4] = fmaxf(m[4], bflo(ra.z) * wa); m[5] = fmaxf(m[5], bfhi(ra.z) * wa);
        m[6] = fmaxf(m[6], bflo(ra.w) * wa); m[7] = fmaxf(m[7], bfhi(ra.w) * wa);
        m[0] = fmaxf(m[0], bflo(rb.x) * wb); m[1] = fmaxf(m[1], bfhi(rb.x) * wb);
        m[2] = fmaxf(m[2], bflo(rb.y) * wb); m[3] = fmaxf(m[3], bfhi(rb.y) * wb);
        m[4] = fmaxf(m[4], bflo(rb.z) * wb); m[5] = fmaxf(m[5], bfhi(rb.z) * wb);
        m[6] = fmaxf(m[6], bflo(rb.w) * wb); m[7] = fmaxf(m[7], bfhi(rb.w) * wb);
    }
}

// ---- K3: per-node gather+max. One wave/node, 4 lane-groups of 16, wave-uniform
// deg branch -> fully-unrolled path. hsrc linear; hnew written SWIZZLED
// (image[r][p] = h[r][p ^ ((r&7)<<3)]) so gemm2 can DMA-stage it linearly.
__global__ __launch_bounds__(256) void node_max(const unsigned short* __restrict__ hb,
        const int* __restrict__ counts, const unsigned* __restrict__ edges,
        unsigned short* __restrict__ hnew)
{
    int node = blockIdx.x * 4 + (threadIdx.x >> 6);
    if (node >= NN) return;
    const int lane = threadIdx.x & 63;
    const int g = lane >> 4, l16 = lane & 15;
    const int deg = min(counts[node], CAP);
    const unsigned* ep = edges + (size_t)node * CAP;
    unsigned p = (lane < deg) ? ep[lane] : 0u;

    float m[8];
    #pragma unroll
    for (int i = 0; i < 8; ++i) m[i] = 0.f;

    if (deg <= 16)      gat<2>(hb, p, deg, g, l16, m);
    else if (deg <= 32) gat<4>(hb, p, deg, g, l16, m);
    else                gat<6>(hb, p, deg, g, l16, m);

    #pragma unroll
    for (int i = 0; i < 8; ++i) {
        m[i] = fmaxf(m[i], __shfl_xor(m[i], 16));
        m[i] = fmaxf(m[i], __shfl_xor(m[i], 32));
    }

    if (g == 0) {
        uint4 o;
        o.x = ((unsigned)(unsigned short)f2bf(m[1]) << 16) | (unsigned short)f2bf(m[0]);
        o.y = ((unsigned)(unsigned short)f2bf(m[3]) << 16) | (unsigned short)f2bf(m[2]);
        o.z = ((unsigned)(unsigned short)f2bf(m[5]) << 16) | (unsigned short)f2bf(m[4]);
        o.w = ((unsigned)(unsigned short)f2bf(m[7]) << 16) | (unsigned short)f2bf(m[6]);
        *(uint4*)(hnew + (size_t)node * 128 + ((l16 * 8) ^ ((node & 7) << 3))) = o;
    }
}

// ---- K4: out = hnew @ lin_w^T + lin_b + bias. A: 16KB LDS via global_load_lds
// (linear dest = pre-swizzled source); W JIT from bf16 image. ----
__global__ __launch_bounds__(512) void gemm2(const unsigned short* __restrict__ Aimg,
        const unsigned short* __restrict__ Wb, const float* __restrict__ b1,
        const float* __restrict__ b2, float* __restrict__ out)
{
    __shared__ short aL[64 * 128];   // 16 KB
    const int tid = threadIdx.x;
    const int lane = tid & 63, wid = tid >> 6;
    const int m0 = blockIdx.x * 64;

    #pragma unroll
    for (int i = 0; i < 2; ++i) {
        const int soff = wid * 1024 + i * 512;        // shorts; dest wave-uniform
        gl16(Aimg + (size_t)m0 * 128 + soff + lane * 8, aL + soff);
    }
    __syncthreads();   // compiler drains vmcnt before s_barrier

    const int l15 = lane & 15, lhi = lane >> 4;
    const int rg = wid & 3, cs = wid >> 2;
    const int r0 = rg * 16;

    short8_t af[4];
    #pragma unroll
    for (int kk = 0; kk < 4; ++kk) {
        const int ar = r0 + l15;
        af[kk] = *(short8_t*)(aL + ((ar * 128 + kk * 32 + lhi * 8) ^ ((ar & 7) << 3)));
    }

    f32x4 acc[4];
    #pragma unroll
    for (int t = 0; t < 4; ++t) acc[t] = f32x4{0.f, 0.f, 0.f, 0.f};

    #pragma unroll
    for (int t = 0; t < 4; ++t) {
        const int br = cs * 64 + t * 16 + l15;
        #pragma unroll
        for (int kk = 0; kk < 4; ++kk) {
            short8_t b = *(const short8_t*)(Wb + br * 128 + kk * 32 + lhi * 8);
            acc[t] = __builtin_amdgcn_mfma_f32_16x16x32_bf16(af[kk], b, acc[t], 0, 0, 0);
        }
    }

    #pragma unroll
    for (int t = 0; t < 4; ++t) {
        const int c = cs * 64 + t * 16 + l15;
        float add = b1[c] + b2[c];
        #pragma unroll
        for (int i = 0; i < 4; ++i) {
            int r = m0 + r0 + lhi * 4 + i;
            if (r < NN) out[(size_t)r * 128 + c] = acc[t][i] + add;
        }
    }
}

extern "C" void kernel_launch(void* const* d_in, const int* in_sizes, int n_in,
                              void* d_out, int out_size, void* d_ws, size_t ws_size,
                              hipStream_t stream) {
    const float* node_feats = (const float*)d_in[0];
    const int*   src        = (const int*)d_in[1];
    const int*   dst        = (const int*)d_in[2];
    const float* ew         = (const float*)d_in[3];
    const float* pool_w     = (const float*)d_in[4];
    const float* pool_b     = (const float*)d_in[5];
    const float* lin_w      = (const float*)d_in[6];
    const float* lin_b      = (const float*)d_in[7];
    const float* bias       = (const float*)d_in[8];
    float* out = (float*)d_out;

    char* w0 = (char*)d_ws;
    unsigned short* hsrc = (unsigned short*)w0;  w0 += (size_t)NN * DD * 2;   // 12.8 MB
    unsigned short* hnew = (unsigned short*)w0;  w0 += (size_t)NN * DD * 2;   // 12.8 MB
    int* counts = (int*)w0;                      w0 += (size_t)NN * 4;        // 200 KB
    unsigned* edges = (unsigned*)w0;             w0 += (size_t)NN * CAP * 4;  // 9.6 MB
    unsigned short* w1b = (unsigned short*)w0;   w0 += (size_t)DD * DD * 2;   // 32 KB
    unsigned short* w2b = (unsigned short*)w0;   w0 += (size_t)DD * DD * 2;   // 32 KB

    prep<<<32, 256, 0, stream>>>(pool_w, lin_w, w1b, w2b);

    const int g_grid = (NN + 63) / 64;   // 782
    gemm1<<<g_grid, 512, 0, stream>>>(node_feats, w1b, pool_b, hsrc, counts);

    bucket<<<(NE + 255) / 256, 256, 0, stream>>>(src, dst, ew, counts, edges);

    node_max<<<(NN + 3) / 4, 256, 0, stream>>>(hsrc, counts, edges, hnew);

    gemm2<<<g_grid, 512, 0, stream>>>(hnew, w2b, lin_b, bias, out);
}

// Round 11
// 167.112 us; speedup vs baseline: 1.1723x; 1.1224x over previous
//
#include <hip/hip_runtime.h>
#include <hip/hip_bf16.h>

#define NN 50000
#define NE 600000
#define DD 128
#define CAP 48               // max degree slots; P(Poisson(12) >= 48) ~ 3e-15

typedef __attribute__((ext_vector_type(8))) short short8_t;
typedef __attribute__((ext_vector_type(4))) short short4_t;
typedef __attribute__((ext_vector_type(4))) float f32x4;

__device__ __forceinline__ short f2bf(float f) {
    union { float f; unsigned u; } v; v.f = f;
    unsigned r = (v.u + 0x7FFFu + ((v.u >> 16) & 1u)) >> 16;
    return (short)r;
}
__device__ __forceinline__ float bflo(unsigned x) { return __uint_as_float(x << 16); }
__device__ __forceinline__ float bfhi(unsigned x) { return __uint_as_float(x & 0xffff0000u); }

// async global->LDS, 16B per lane; dest must be wave-uniform base (HW adds lane*16)
__device__ __forceinline__ void gl16(const void* g, void* l) {
    __builtin_amdgcn_global_load_lds(
        (const __attribute__((address_space(1))) unsigned*)g,
        (__attribute__((address_space(3))) unsigned*)l, 16, 0, 0);
}

// ---- K1: hsrc_swz = relu(X @ pool_w^T + pool_b) (bf16, row-swizzled image) ----
// Side duties: zero counts (PADDED: 1 counter per 64B line); block 0 builds
// swizzled bf16 image of lin_w for K4.
// Swizzle: image[r][p] = h[r][p ^ ((r&7)<<3)]  (involution within each 256B row).
__global__ __launch_bounds__(512) void gemm1(const float* __restrict__ A,
        const float* __restrict__ Wp, const float* __restrict__ b1,
        unsigned short* __restrict__ hout, const float* __restrict__ Wl,
        unsigned short* __restrict__ wimg, int* __restrict__ counts)
{
    __shared__ short aL[128 * 128];   // 32 KB
    __shared__ short wL[128 * 128];   // 32 KB
    const int tid = threadIdx.x;
    const int m0 = blockIdx.x * 128;

    {   // zero padded counts (replaces a memset dispatch; stream-ordered)
        int gid = blockIdx.x * 512 + tid;
        if (gid < NN) counts[gid << 4] = 0;
    }
    if (blockIdx.x == 0) {   // build lin_w swizzled bf16 image (32 KB)
        #pragma unroll
        for (int i = 0; i < 8; ++i) {
            int idx = (i * 512 + tid) * 4;               // output short4 index
            int row = idx >> 7;
            int kk = (idx & 127) ^ ((row & 7) << 3);     // inverse swizzle (involution)
            float4 v = *(const float4*)(Wl + row * 128 + kk);
            short4_t s4 = { f2bf(v.x), f2bf(v.y), f2bf(v.z), f2bf(v.w) };
            *(short4_t*)(wimg + idx) = s4;
        }
    }

    // stage A tile (128x128 f32 -> bf16, swizzled)
    #pragma unroll
    for (int i = 0; i < 8; ++i) {
        int flat = i * 2048 + tid * 4;
        int row = flat >> 7, k = flat & 127;
        int gr = m0 + row;
        float4 v = make_float4(0.f, 0.f, 0.f, 0.f);
        if (gr < NN) v = *(const float4*)(A + (size_t)gr * 128 + k);
        short4_t s4 = { f2bf(v.x), f2bf(v.y), f2bf(v.z), f2bf(v.w) };
        *(short4_t*)(aL + ((row * 128 + k) ^ ((row & 7) << 3))) = s4;
    }
    // stage pool_w
    #pragma unroll
    for (int i = 0; i < 8; ++i) {
        int flat = i * 2048 + tid * 4;
        int row = flat >> 7, k = flat & 127;
        float4 v = *(const float4*)(Wp + flat);
        short4_t s4 = { f2bf(v.x), f2bf(v.y), f2bf(v.z), f2bf(v.w) };
        *(short4_t*)(wL + ((row * 128 + k) ^ ((row & 7) << 3))) = s4;
    }
    __syncthreads();

    const int lane = tid & 63, wid = tid >> 6;
    const int l15 = lane & 15, lhi = lane >> 4;
    const int r0 = wid * 16;
    f32x4 acc[8];
    #pragma unroll
    for (int t = 0; t < 8; ++t) acc[t] = f32x4{0.f, 0.f, 0.f, 0.f};

    #pragma unroll
    for (int kk = 0; kk < 4; ++kk) {
        const int k0 = kk * 32 + lhi * 8;
        const int ar = r0 + l15;
        short8_t a = *(short8_t*)(aL + ((ar * 128 + k0) ^ ((ar & 7) << 3)));
        #pragma unroll
        for (int t = 0; t < 8; ++t) {
            const int br = t * 16 + l15;
            short8_t b = *(short8_t*)(wL + ((br * 128 + k0) ^ ((br & 7) << 3)));
            acc[t] = __builtin_amdgcn_mfma_f32_16x16x32_bf16(a, b, acc[t], 0, 0, 0);
        }
    }

    // epilogue: relu, write bf16 SWIZZLED (image layout for node_max/gemm2 DMA)
    #pragma unroll
    for (int t = 0; t < 8; ++t) {
        const int c = t * 16 + l15;
        float add = b1[c];
        #pragma unroll
        for (int i = 0; i < 4; ++i) {
            int r = m0 + r0 + lhi * 4 + i;
            if (r < NN) {
                float v = fmaxf(acc[t][i] + add, 0.f);
                hout[(size_t)r * 128 + (c ^ ((r & 7) << 3))] = (unsigned short)f2bf(v);
            }
        }
    }
}

// ---- K2: bucket scatter, packed 4B records: (src << 16) | bf16_bits(w) ----
// Counters PADDED to 1/64B-line (kills TCC same-line atomic serialization);
// ILP x4: 4 independent load->atomic->store chains per thread.
#define BT 150000            // NE/4 threads
__global__ __launch_bounds__(256) void bucket(const int* __restrict__ src,
        const int* __restrict__ dst, const float* __restrict__ ew,
        int* __restrict__ counts, unsigned* __restrict__ edges)
{
    const int t = blockIdx.x * 256 + threadIdx.x;
    if (t >= BT) return;
    int d[4], s[4]; float w[4];
    #pragma unroll
    for (int u = 0; u < 4; ++u) {
        const int e = t + u * BT;
        d[u] = dst[e]; s[u] = src[e]; w[u] = ew[e];
    }
    int pos[4];
    #pragma unroll
    for (int u = 0; u < 4; ++u)
        pos[u] = atomicAdd(&counts[d[u] << 4], 1);
    #pragma unroll
    for (int u = 0; u < 4; ++u)
        if (pos[u] < CAP)
            edges[(size_t)d[u] * CAP + pos[u]] =
                ((unsigned)s[u] << 16) | (unsigned short)f2bf(w[u]);
}

// gather NIT*8 edges fully unrolled (2*NIT independent 16B loads in flight).
// Reading swizzled image at (d ^ swz(s)) returns dims d..d+7 (involution).
template<int NIT>
__device__ __forceinline__ void gat(const unsigned short* __restrict__ hb,
        unsigned p, int deg, int g, int l16, float* m)
{
    #pragma unroll
    for (int it = 0; it < NIT; ++it) {
        const int ia = it * 8 + g, ib = it * 8 + 4 + g;
        unsigned pa = __shfl(p, ia), pb = __shfl(p, ib);
        float wa = (ia < deg) ? __uint_as_float(pa << 16) : 0.f;
        float wb = (ib < deg) ? __uint_as_float(pb << 16) : 0.f;
        unsigned sa = pa >> 16, sb = pb >> 16;
        uint4 ra = *(const uint4*)(hb + (size_t)sa * 128 + ((l16 * 8) ^ ((sa & 7) << 3)));
        uint4 rb = *(const uint4*)(hb + (size_t)sb * 128 + ((l16 * 8) ^ ((sb & 7) << 3)));
        m[0] = fmaxf(m[0], bflo(ra.x) * wa); m[1] = fmaxf(m[1], bfhi(ra.x) * wa);
        m[2] = fmaxf(m[2], bflo(ra.y) * wa); m[3] = fmaxf(m[3], bfhi(ra.y) * wa);
        m[4] = fmaxf(m[4], bflo(ra.z) * wa); m[5] = fmaxf(m[5], bfhi(ra.z) * wa);
        m[6] = fmaxf(m[6], bflo(ra.w) * wa); m[7] = fmaxf(m[7], bfhi(ra.w) * wa);
        m[0] = fmaxf(m[0], bflo(rb.x) * wb); m[1] = fmaxf(m[1], bfhi(rb.x) * wb);
        m[2] = fmaxf(m[2], bflo(rb.y) * wb); m[3] = fmaxf(m[3], bfhi(rb.y) * wb);
        m[4] = fmaxf(m[4], bflo(rb.z) * wb); m[5] = fmaxf(m[5], bfhi(rb.z) * wb);
        m[6] = fmaxf(m[6], bflo(rb.w) * wb); m[7] = fmaxf(m[7], bfhi(rb.w) * wb);
    }
}

// ---- K3: per-node gather+max. One wave/node; 4 lane-groups of 16; wave-uniform
// deg branch picks a fully-unrolled path (all loads issued before first wait).
// Input and output are row-swizzled bf16 images. Padded counter read.
__global__ __launch_bounds__(256) void node_max(const unsigned short* __restrict__ hb,
        const int* __restrict__ counts, const unsigned* __restrict__ edges,
        unsigned short* __restrict__ hnew)
{
    int node = blockIdx.x * 4 + (threadIdx.x >> 6);
    if (node >= NN) return;
    const int lane = threadIdx.x & 63;
    const int g = lane >> 4, l16 = lane & 15;
    const int deg = min(counts[node << 4], CAP);
    const unsigned* ep = edges + (size_t)node * CAP;
    unsigned p = (lane < deg) ? ep[lane] : 0u;

    float m[8];
    #pragma unroll
    for (int i = 0; i < 8; ++i) m[i] = 0.f;

    if (deg <= 16)      gat<2>(hb, p, deg, g, l16, m);
    else if (deg <= 32) gat<4>(hb, p, deg, g, l16, m);
    else                gat<6>(hb, p, deg, g, l16, m);

    #pragma unroll
    for (int i = 0; i < 8; ++i) {
        m[i] = fmaxf(m[i], __shfl_xor(m[i], 16));
        m[i] = fmaxf(m[i], __shfl_xor(m[i], 32));
    }

    if (g == 0) {
        uint4 o;
        o.x = ((unsigned)(unsigned short)f2bf(m[1]) << 16) | (unsigned short)f2bf(m[0]);
        o.y = ((unsigned)(unsigned short)f2bf(m[3]) << 16) | (unsigned short)f2bf(m[2]);
        o.z = ((unsigned)(unsigned short)f2bf(m[5]) << 16) | (unsigned short)f2bf(m[4]);
        o.w = ((unsigned)(unsigned short)f2bf(m[7]) << 16) | (unsigned short)f2bf(m[6]);
        *(uint4*)(hnew + (size_t)node * 128 + ((l16 * 8) ^ ((node & 7) << 3))) = o;
    }
}

// ---- K4: out = hnew @ lin_w^T + lin_b + bias. A and W are pre-swizzled bf16
// images -> pure global_load_lds staging (linear dest = pre-swz source, G15/#21).
__global__ __launch_bounds__(512) void gemm2(const unsigned short* __restrict__ Aimg,
        const unsigned short* __restrict__ wimg, const float* __restrict__ b1,
        const float* __restrict__ b2, float* __restrict__ out)
{
    __shared__ short aL[128 * 128];
    __shared__ short wL[128 * 128];
    const int tid = threadIdx.x;
    const int lane = tid & 63, wid = tid >> 6;
    const int m0 = blockIdx.x * 128;

    #pragma unroll
    for (int i = 0; i < 4; ++i) {
        const int soff = i * 4096 + wid * 512;       // short offset; dest wave-uniform
        gl16(Aimg + (size_t)m0 * 128 + soff + lane * 8, aL + soff);
        gl16(wimg + soff + lane * 8, wL + soff);
    }
    __syncthreads();   // drains vmcnt (compiler emits s_waitcnt vmcnt(0) before barrier)

    const int l15 = lane & 15, lhi = lane >> 4;
    const int r0 = wid * 16;
    f32x4 acc[8];
    #pragma unroll
    for (int t = 0; t < 8; ++t) acc[t] = f32x4{0.f, 0.f, 0.f, 0.f};

    #pragma unroll
    for (int kk = 0; kk < 4; ++kk) {
        const int k0 = kk * 32 + lhi * 8;
        const int ar = r0 + l15;
        short8_t a = *(short8_t*)(aL + ((ar * 128 + k0) ^ ((ar & 7) << 3)));
        #pragma unroll
        for (int t = 0; t < 8; ++t) {
            const int br = t * 16 + l15;
            short8_t b = *(short8_t*)(wL + ((br * 128 + k0) ^ ((br & 7) << 3)));
            acc[t] = __builtin_amdgcn_mfma_f32_16x16x32_bf16(a, b, acc[t], 0, 0, 0);
        }
    }

    #pragma unroll
    for (int t = 0; t < 8; ++t) {
        const int c = t * 16 + l15;
        float add = b1[c] + b2[c];
        #pragma unroll
        for (int i = 0; i < 4; ++i) {
            int r = m0 + r0 + lhi * 4 + i;
            if (r < NN) out[(size_t)r * 128 + c] = acc[t][i] + add;
        }
    }
}

extern "C" void kernel_launch(void* const* d_in, const int* in_sizes, int n_in,
                              void* d_out, int out_size, void* d_ws, size_t ws_size,
                              hipStream_t stream) {
    const float* node_feats = (const float*)d_in[0];
    const int*   src        = (const int*)d_in[1];
    const int*   dst        = (const int*)d_in[2];
    const float* ew         = (const float*)d_in[3];
    const float* pool_w     = (const float*)d_in[4];
    const float* pool_b     = (const float*)d_in[5];
    const float* lin_w      = (const float*)d_in[6];
    const float* lin_b      = (const float*)d_in[7];
    const float* bias       = (const float*)d_in[8];
    float* out = (float*)d_out;

    char* w0 = (char*)d_ws;
    unsigned short* hsrc = (unsigned short*)w0;  w0 += (size_t)NN * DD * 2;     // 12.8 MB
    unsigned short* hnew = (unsigned short*)w0;  w0 += (size_t)NN * DD * 2;     // 12.8 MB
    int* counts = (int*)w0;                      w0 += (size_t)NN * 64;         // 3.2 MB (padded)
    unsigned* edges = (unsigned*)w0;             w0 += (size_t)NN * CAP * 4;    // 9.6 MB
    unsigned short* wimg = (unsigned short*)w0;  w0 += (size_t)DD * DD * 2;     // 32 KB

    const int gemm_grid = (NN + 127) / 128;   // 391
    gemm1<<<gemm_grid, 512, 0, stream>>>(node_feats, pool_w, pool_b, hsrc,
                                         lin_w, wimg, counts);

    bucket<<<(BT + 255) / 256, 256, 0, stream>>>(src, dst, ew, counts, edges);

    node_max<<<(NN + 3) / 4, 256, 0, stream>>>(hsrc, counts, edges, hnew);

    gemm2<<<gemm_grid, 512, 0, stream>>>(hnew, wimg, lin_b, bias, out);
}